// Round 11
// baseline (1559.765 us; speedup 1.0000x reference)
//
#include <hip/hip_runtime.h>
#include <hip/hip_bf16.h>
#include <math.h>

#define NNODES 50000
#define NEDGES 800000
#define HD     256   // HEADS*DHEAD
#define CW     384   // comb width: q(256) | qwe(64) | skip(64)
#define NTOT   896   // Wc rows: q(256)|qwe(64)|skip(64)|v(256)|k(256)
#define QS     0.18033688011112042f   // 0.125 * log2(e): fold softmax scale into exp2

typedef __hip_bfloat16 bf16;
typedef unsigned short u16;
typedef unsigned char  u8;
typedef unsigned int   u32;
typedef __attribute__((ext_vector_type(8))) short bf16x8;
typedef __attribute__((ext_vector_type(4))) float f32x4;
typedef __attribute__((ext_vector_type(2))) float f32x2;

__device__ __forceinline__ float lo16f(u32 u) { return __uint_as_float(u << 16); }
__device__ __forceinline__ float hi16f(u32 u) { return __uint_as_float(u & 0xFFFF0000u); }
__device__ __forceinline__ short f2s(float v) { __hip_bfloat16 h = __float2bfloat16(v); return *(short*)&h; }

// async global->LDS, 16B per lane; lds dest is wave-uniform base + lane*16 (linear)
__device__ __forceinline__ void gload_lds16(const void* g, void* l) {
    __builtin_amdgcn_global_load_lds(
        (const __attribute__((address_space(1))) void*)g,
        (__attribute__((address_space(3))) void*)l, 16, 0, 0);
}

// VALU cross-lane add within 16-lane groups
template<int CTRL>
__device__ __forceinline__ float dppadd(float x) {
    int t = __builtin_amdgcn_update_dpp(0, __float_as_int(x), CTRL, 0xF, 0xF, true);
    return x + __int_as_float(t);
}

// ---------------- CSR build ----------------
__global__ void hist_kernel(const int* __restrict__ dst, int* __restrict__ deg, int E) {
    int e = blockIdx.x * 256 + threadIdx.x;
    if (e < E) atomicAdd(&deg[dst[e]], 1);
}

__global__ void scanA(const int* __restrict__ deg, int* __restrict__ locincl,
                      int* __restrict__ blocksum, int n) {
    int tid = threadIdx.x;
    int i = blockIdx.x * 256 + tid;
    int v = (i < n) ? deg[i] : 0;
    int lane = tid & 63, w = tid >> 6;
    int s = v;
    #pragma unroll
    for (int off = 1; off < 64; off <<= 1) {
        int t = __shfl_up(s, off);
        if (lane >= off) s += t;
    }
    __shared__ int wsum[4];
    if (lane == 63) wsum[w] = s;
    __syncthreads();
    for (int ww = 0; ww < w; ww++) s += wsum[ww];
    if (i < n) locincl[i] = s;
    if (tid == 255) blocksum[blockIdx.x] = s;
}

__global__ void scanB(const int* __restrict__ blocksum, int* __restrict__ blockoff,
                      int nb, int* __restrict__ rowptr, int n) {
    int tid = threadIdx.x;
    int v = (tid < nb) ? blocksum[tid] : 0;
    int lane = tid & 63, w = tid >> 6;
    int s = v;
    #pragma unroll
    for (int off = 1; off < 64; off <<= 1) {
        int t = __shfl_up(s, off);
        if (lane >= off) s += t;
    }
    __shared__ int wsum[4];
    if (lane == 63) wsum[w] = s;
    __syncthreads();
    for (int ww = 0; ww < w; ww++) s += wsum[ww];
    if (tid < nb) blockoff[tid] = s - v;
    if (tid == 255) rowptr[n] = s;
}

__global__ void scanC(const int* __restrict__ deg, const int* __restrict__ locincl,
                      const int* __restrict__ blockoff,
                      int* __restrict__ rowptr, int* __restrict__ cursor, int n) {
    int i = blockIdx.x * 256 + threadIdx.x;
    if (i < n) {
        int ex = locincl[i] - deg[i] + blockoff[blockIdx.x];
        rowptr[i] = ex;
        cursor[i] = ex;
    }
}

// scatter + eattr permute fused: eattr read SEQUENTIALLY by edge id (64-B coalesced),
// converted to bf16 and written once to CSR position (random 32-B write).
__global__ void scatter_kernel(const int* __restrict__ src, const int* __restrict__ dst,
                               int* __restrict__ cursor, int* __restrict__ csr_src,
                               const float* __restrict__ eattr, u16* __restrict__ eattr_c, int E) {
    int e = blockIdx.x * 256 + threadIdx.x;
    if (e < E) {
        int d = dst[e];
        int p = atomicAdd(&cursor[d], 1);
        csr_src[p] = src[e];
        const float4* er = (const float4*)(eattr + (size_t)e * 16);
        float4 a = er[0], b = er[1], c = er[2], f = er[3];
        union { u16 s[16]; uint4 u[2]; } t;
        t.s[0]  = (u16)f2s(a.x); t.s[1]  = (u16)f2s(a.y); t.s[2]  = (u16)f2s(a.z); t.s[3]  = (u16)f2s(a.w);
        t.s[4]  = (u16)f2s(b.x); t.s[5]  = (u16)f2s(b.y); t.s[6]  = (u16)f2s(b.z); t.s[7]  = (u16)f2s(b.w);
        t.s[8]  = (u16)f2s(c.x); t.s[9]  = (u16)f2s(c.y); t.s[10] = (u16)f2s(c.z); t.s[11] = (u16)f2s(c.w);
        t.s[12] = (u16)f2s(f.x); t.s[13] = (u16)f2s(f.y); t.s[14] = (u16)f2s(f.z); t.s[15] = (u16)f2s(f.w);
        uint4* dstp = (uint4*)((u8*)eattr_c + (size_t)p * 32);
        dstp[0] = t.u[0];
        dstp[1] = t.u[1];
    }
}

// ---- x fp32 -> bf16 (once) ----
__global__ void xcast(const float* __restrict__ x, u16* __restrict__ xb) {
    int i = blockIdx.x * 256 + threadIdx.x;
    const float4* p = (const float4*)(x + (size_t)i * 8);
    float4 a = p[0], b = p[1];
    union { u16 s[8]; uint4 u; } t;
    t.s[0] = (u16)f2s(a.x); t.s[1] = (u16)f2s(a.y); t.s[2] = (u16)f2s(a.z); t.s[3] = (u16)f2s(a.w);
    t.s[4] = (u16)f2s(b.x); t.s[5] = (u16)f2s(b.y); t.s[6] = (u16)f2s(b.z); t.s[7] = (u16)f2s(b.w);
    *(uint4*)(xb + (size_t)i * 8) = t.u;
}

// ---- pack: 896 rows n-major bf16 [NTOT][K] + fp32 bias ----
// rows: q(0..255)*QS | qwe(256..319)*QS | skip(320..383) | v(384..639) | k(640..895)
__global__ void pack_all(const float* __restrict__ Wq, const float* __restrict__ bq,
                         const float* __restrict__ Wk, const float* __restrict__ bk,
                         const float* __restrict__ Wv, const float* __restrict__ bv,
                         const float* __restrict__ We,
                         const float* __restrict__ Ws, const float* __restrict__ bs,
                         bf16* __restrict__ Wc, float* __restrict__ b, int K) {
    int n = blockIdx.x, c = threadIdx.x;
    float v, bb;
    if (n < 256)      { v = Wq[(size_t)c * 256 + n] * QS;    bb = bq[n] * QS; }
    else if (n < 320) {
        int t = n - 256, h = t >> 4, j = t & 15;
        float s = 0.f, sb = 0.f;
        #pragma unroll 8
        for (int d = 0; d < 64; d++) {
            float wv = We[j * HD + h * 64 + d];
            s += Wq[(size_t)c * 256 + h * 64 + d] * wv;
            sb += bq[h * 64 + d] * wv;
        }
        v = s * QS; bb = sb * QS;
    }
    else if (n < 384) { v = Ws[(size_t)c * 64  + (n - 320)]; bb = bs[n - 320]; }
    else if (n < 640) { v = Wv[(size_t)c * 256 + (n - 384)]; bb = bv[n - 384]; }
    else              { v = Wk[(size_t)c * 256 + (n - 640)]; bb = bk[n - 640]; }
    Wc[(size_t)n * K + c] = __float2bfloat16(v);
    if (c == 0) b[n] = bb;
}

// ---------------- MFMA GEMM v4 (unchanged) ----------------
template<int K>
__global__ void __launch_bounds__(256) gemm_v4(
    const u16* __restrict__ A, const bf16* __restrict__ Wc, const float* __restrict__ bias,
    bf16* __restrict__ comb, u8* __restrict__ kv)
{
    constexpr int KS    = K / 32;
    constexpr int ITERS = 4;
    constexpr int ROWB  = K * 2;
    constexpr int TILEB = 64 * ROWB;
    constexpr int WSEG  = TILEB / 4;
    constexpr int NINST = WSEG / 1024;
    __shared__ __align__(16) u8 Ab[2][TILEB];
    __shared__ __align__(16) u8 TrB[4][2560];
    int tid = threadIdx.x, w = tid >> 6, lane = tid & 63;
    int cl = lane & 15, aq = lane >> 4;
    int chunk = blockIdx.x;
    int slab = blockIdx.y * (64 * ITERS);
    u8* myT = TrB[w];

    bf16x8 bfr[4][KS];
    #pragma unroll
    for (int t = 0; t < 4; t++)
        #pragma unroll
        for (int ks = 0; ks < KS; ks++)
            bfr[t][ks] = *(const bf16x8*)((const u16*)Wc +
                         (size_t)(chunk * 64 + t * 16 + cl) * K + ks * 32 + aq * 8);

    float4 bv[4];
    #pragma unroll
    for (int t = 0; t < 4; t++) bv[t] = *(const float4*)&bias[chunk * 64 + t * 16 + aq * 4];

    auto STAGE = [&](int b, int it) {
        int m0 = slab + it * 64;
        #pragma unroll
        for (int i = 0; i < NINST; i++) {
            int off = w * WSEG + i * 1024;
            int rowbase = off / ROWB;
            int row, gran;
            if constexpr (K == 64) { row = rowbase + (lane >> 3); gran = lane & 7;  }
            else                   { row = rowbase + (lane >> 4); gran = lane & 15; }
            int gr = m0 + row; if (gr >= NNODES) gr = NNODES - 1;
            int sg = gran ^ (row & 7);
            gload_lds16((const u8*)A + (size_t)gr * ROWB + sg * 16, Ab[b] + off);
        }
    };

    STAGE(0, 0);
    __syncthreads();
    int cur = 0;
    #pragma unroll
    for (int it = 0; it < ITERS; it++) {
        if (it + 1 < ITERS) STAGE(cur ^ 1, it + 1);

        int rowt = w * 16 + cl;
        bf16x8 a[KS];
        #pragma unroll
        for (int ks = 0; ks < KS; ks++)
            a[ks] = *(const bf16x8*)&Ab[cur][rowt * ROWB + (((ks * 4 + aq) ^ (rowt & 7)) << 4)];

        f32x4 acc[4] = {};
        #pragma unroll
        for (int t = 0; t < 4; t++)
            #pragma unroll
            for (int ks = 0; ks < KS; ks++)
                acc[t] = __builtin_amdgcn_mfma_f32_16x16x32_bf16(bfr[t][ks], a[ks], acc[t], 0, 0, 0);

        if (chunk < 10) {
            #pragma unroll
            for (int t = 0; t < 4; t++) {
                u32 lo = (u32)(u16)f2s(acc[t][0] + bv[t].x) | ((u32)(u16)f2s(acc[t][1] + bv[t].y) << 16);
                u32 hi = (u32)(u16)f2s(acc[t][2] + bv[t].z) | ((u32)(u16)f2s(acc[t][3] + bv[t].w) << 16);
                *(uint2*)(myT + cl * 160 + t * 32 + aq * 8) = make_uint2(lo, hi);
            }
            #pragma unroll
            for (int i = 0; i < 2; i++) {
                int r = i * 8 + (lane >> 3);
                uint4 vv = *(const uint4*)(myT + r * 160 + (lane & 7) * 16);
                int gr = slab + it * 64 + w * 16 + r;
                if (gr < NNODES) {
                    u8* dst = (chunk < 6) ? (u8*)comb + (size_t)gr * (CW * 2) + chunk * 128
                                          : kv + (size_t)gr * 768 + (chunk - 6) * 128;
                    *(uint4*)(dst + (lane & 7) * 16) = vv;
                }
            }
        } else {
            #pragma unroll
            for (int t = 0; t < 4; t++) {
                u32 pk = __builtin_amdgcn_cvt_pk_fp8_f32(acc[t][0] + bv[t].x, acc[t][1] + bv[t].y, 0, false);
                pk = __builtin_amdgcn_cvt_pk_fp8_f32(acc[t][2] + bv[t].z, acc[t][3] + bv[t].w, pk, true);
                *(u32*)(myT + cl * 80 + (t * 4 + aq) * 4) = pk;
            }
            {
                int r = lane >> 2;
                uint4 vv = *(const uint4*)(myT + r * 80 + (lane & 3) * 16);
                int gr = slab + it * 64 + w * 16 + r;
                if (gr < NNODES)
                    *(uint4*)(kv + (size_t)gr * 768 + 512 + (chunk - 10) * 64 + (lane & 3) * 16) = vv;
            }
        }
        __syncthreads();
        cur ^= 1;
    }
}

// ---------------- persistent work-stealing node aggregation ----------------
// 2048 blocks x 4 waves; each WAVE steals nodes in chunks of 2 via atomicAdd
// (lane0 + shfl broadcast). No wave idles behind a slow sibling; steal order
// ~= node order so eattr_c reads stay sequential. Per-node body unchanged.
__global__ void __launch_bounds__(256) node_fused(
    int* __restrict__ ctr,
    const int* __restrict__ rowptr, const int* __restrict__ csr_src,
    const u16* __restrict__ eattr_c, const u16* __restrict__ comb,
    const u8* __restrict__ kv,
    const float* __restrict__ We, const float* __restrict__ lng, const float* __restrict__ lnb,
    bf16* __restrict__ outB, float* __restrict__ outF)
{
    int tid = threadIdx.x, w = tid >> 6, lane = tid & 63;
    int hg = lane >> 4, j16 = lane & 15, coff = 4 * lane;
    __shared__ float sAV[4][256];
    __shared__ float sAE[4][64];

    u32 vo = (u32)coff * 2u;          // byte offset in v region (0..504)
    u32 eo = (u32)j16 * 2u;           // bf16 byte offset in eattr_c row (0..30)
    const int* cs = csr_src;

    for (;;) {
        int base = 0;
        if (lane == 0) base = atomicAdd(ctr, 2);
        base = __shfl(base, 0);
        if (base >= NNODES) break;
        int nend = base + 2; if (nend > NNODES) nend = NNODES;

        for (int n = base; n < nend; n++) {
            const u16* crow = comb + (size_t)n * CW;
            uint2 qv = *(const uint2*)(crow + coff);     // q (pre-scaled by QS)
            float qf0 = lo16f(qv.x), qf1 = hi16f(qv.x), qf2 = lo16f(qv.y), qf3 = hi16f(qv.y);
            float qwe_r = __uint_as_float((u32)crow[256 + lane] << 16);

            int e0 = __builtin_amdgcn_readfirstlane(rowptr[n]);
            int e1 = __builtin_amdgcn_readfirstlane(rowptr[n + 1]);

            float ss = 0.f, av0 = 0.f, av1 = 0.f, av2 = 0.f, av3 = 0.f, ae = 0.f;

            auto EDGE = [&](int sm, int pos) {
                u32 s = (u32)__builtin_amdgcn_readfirstlane(sm);   // wave-uniform -> SGPR
                const u8* kvp = kv + (size_t)s * 768u;
                uint2 vw = *(const uint2*)(kvp + vo);
                u32   kw = *(const u32*)  (kvp + 512u + (u32)coff);
                float ea = lo16f((u32)*(const u16*)((const u8*)eattr_c + (size_t)(u32)pos * 32u + eo));
                f32x2 k01 = __builtin_amdgcn_cvt_pk_f32_fp8(kw, false);
                f32x2 k23 = __builtin_amdgcn_cvt_pk_f32_fp8(kw, true);
                float part = qf0 * k01[0] + qf1 * k01[1] + qf2 * k23[0] + qf3 * k23[1] + qwe_r * ea;
                part = dppadd<0xB1>(part);    // xor 1
                part = dppadd<0x4E>(part);    // xor 2
                part = dppadd<0x141>(part);   // xor 4 (row_half_mirror)
                part = dppadd<0x140>(part);   // xor 8 (row_mirror)
                float alpha = __builtin_amdgcn_exp2f(part);
                ss += alpha;
                ae += alpha * ea;
                av0 += alpha * lo16f(vw.x); av1 += alpha * hi16f(vw.x);
                av2 += alpha * lo16f(vw.y); av3 += alpha * hi16f(vw.y);
            };

            int i = e0;
            int m0 = 0, m1 = 0, m2 = 0, m3 = 0, m4 = 0, m5 = 0, m6 = 0, m7 = 0;
            if (i + 7 < e1) {
                m0 = cs[i];     m1 = cs[i + 1]; m2 = cs[i + 2]; m3 = cs[i + 3];
                m4 = cs[i + 4]; m5 = cs[i + 5]; m6 = cs[i + 6]; m7 = cs[i + 7];
            }
            for (; i + 15 < e1; i += 8) {
                int n0 = cs[i + 8],  n1 = cs[i + 9],  n2 = cs[i + 10], n3 = cs[i + 11];
                int n4 = cs[i + 12], n5 = cs[i + 13], n6 = cs[i + 14], n7 = cs[i + 15];
                EDGE(m0, i);     EDGE(m1, i + 1); EDGE(m2, i + 2); EDGE(m3, i + 3);
                EDGE(m4, i + 4); EDGE(m5, i + 5); EDGE(m6, i + 6); EDGE(m7, i + 7);
                m0 = n0; m1 = n1; m2 = n2; m3 = n3; m4 = n4; m5 = n5; m6 = n6; m7 = n7;
            }
            if (i + 7 < e1) {
                EDGE(m0, i);     EDGE(m1, i + 1); EDGE(m2, i + 2); EDGE(m3, i + 3);
                EDGE(m4, i + 4); EDGE(m5, i + 5); EDGE(m6, i + 6); EDGE(m7, i + 7);
                i += 8;
            }
            for (; i < e1; ++i) EDGE(cs[i], i);

            // epilogue (per-wave LDS slice; same-wave DS ordered, no barrier)
            float inv = (ss > 0.f) ? 1.f / ss : 0.f;
            *(float4*)&sAV[w][coff] = make_float4(av0 * inv, av1 * inv, av2 * inv, av3 * inv);
            sAE[w][lane] = ae * inv;

            int d = lane;
            float val = 0.f;
            #pragma unroll
            for (int h = 0; h < 4; h++) {
                float xv = sAV[w][h * 64 + d];
                #pragma unroll
                for (int j = 0; j < 16; j++) xv += sAE[w][h * 16 + j] * We[j * HD + h * 64 + d];
                val += xv;
            }
            val = val * 0.25f + __uint_as_float((u32)crow[320 + d] << 16);   // head mean + skip

            float m = val;
            #pragma unroll
            for (int off = 1; off < 64; off <<= 1) m += __shfl_xor(m, off);
            m *= (1.f / 64.f);
            float diff = val - m;
            float vr = diff * diff;
            #pragma unroll
            for (int off = 1; off < 64; off <<= 1) vr += __shfl_xor(vr, off);
            vr *= (1.f / 64.f);
            float y = diff * rsqrtf(vr + 1e-5f) * lng[d] + lnb[d];
            float ge = 0.5f * y * (1.f + erff(y * 0.70710678118654752f));    // exact GELU
            if (outF) outF[(size_t)n * 64 + d] = ge;
            else      outB[(size_t)n * 64 + d] = __float2bfloat16(ge);
        }
    }
}

extern "C" void kernel_launch(void* const* d_in, const int* in_sizes, int n_in,
                              void* d_out, int out_size, void* d_ws, size_t ws_size,
                              hipStream_t stream)
{
    const float* x     = (const float*)d_in[0];
    const int*   eidx  = (const int*)d_in[1];
    const float* eattr = (const float*)d_in[2];
    struct P { const float *Wq,*bq,*Wk,*bk,*Wv,*bv,*We,*Ws,*bs; };
    P p[3];
    for (int l = 0; l < 3; l++) {
        int base = 3 + l * 9;
        p[l].Wq = (const float*)d_in[base + 0]; p[l].bq = (const float*)d_in[base + 1];
        p[l].Wk = (const float*)d_in[base + 2]; p[l].bk = (const float*)d_in[base + 3];
        p[l].Wv = (const float*)d_in[base + 4]; p[l].bv = (const float*)d_in[base + 5];
        p[l].We = (const float*)d_in[base + 6];
        p[l].Ws = (const float*)d_in[base + 7]; p[l].bs = (const float*)d_in[base + 8];
    }
    const float* lng = (const float*)d_in[30];
    const float* lnb = (const float*)d_in[31];

    // Workspace: ~127 MB
    char* ws = (char*)d_ws;
    size_t off = 0;
    auto alloc = [&](size_t bytes) { void* pp = ws + off; off += (bytes + 255) & ~(size_t)255; return pp; };
    int*   rowptr   = (int*)  alloc((NNODES + 1) * 4);
    int*   cursor   = (int*)  alloc(NNODES * 4);
    int*   deg      = (int*)  alloc(NNODES * 4);
    int*   blocksum = (int*)  alloc(256 * 4);
    int*   blockoff = (int*)  alloc(256 * 4);
    int*   nctr     = (int*)  alloc(8 * 4);                     // per-layer steal counters
    int*   csr_src  = (int*)  alloc((size_t)NEDGES * 4);        // 3.2 MB
    u16*   eattr_c  = (u16*)  alloc((size_t)NEDGES * 16 * 2);   // 25.6 MB bf16, CSR order
    bf16*  hbuf     = (bf16*) alloc((size_t)NNODES * 64 * 2);   // 6.4 MB
    u16*   xb       = (u16*)  alloc((size_t)NNODES * 128 * 2);  // 12.8 MB bf16 x
    bf16*  comb     = (bf16*) alloc((size_t)NNODES * CW * 2);   // 38.4 MB: q|qwe|skip
    u8*    kv       = (u8*)   alloc((size_t)NNODES * 768);      // 38.4 MB: v(512B)|k(256B)
    bf16*  Wc       = (bf16*) alloc((size_t)NTOT * 128 * 2);    // 229 KB
    float* b896     = (float*)alloc(NTOT * 4);
    (void)ws_size;

    const int* srcArr = eidx;           // edge_index[0]
    const int* dstArr = eidx + NEDGES;  // edge_index[1]

    // CSR build (+fused eattr permute) + x cast
    int NB = (NNODES + 255) / 256;
    (void)hipMemsetAsync(deg, 0, NNODES * 4, stream);
    (void)hipMemsetAsync(nctr, 0, 32, stream);
    hist_kernel<<<(NEDGES + 255) / 256, 256, 0, stream>>>(dstArr, deg, NEDGES);
    scanA<<<NB, 256, 0, stream>>>(deg, cursor, blocksum, NNODES);
    scanB<<<1, 256, 0, stream>>>(blocksum, blockoff, NB, rowptr, NNODES);
    scanC<<<NB, 256, 0, stream>>>(deg, cursor, blockoff, rowptr, cursor, NNODES);
    scatter_kernel<<<(NEDGES + 255) / 256, 256, 0, stream>>>(srcArr, dstArr, cursor,
                                                             csr_src, eattr, eattr_c, NEDGES);
    xcast<<<(NNODES * 128 / 8 + 255) / 256, 256, 0, stream>>>(x, xb);

    int NBY = (NNODES + 255) / 256;   // 196 m-slabs of 256 rows
    int fins[3] = {128, 64, 64};

    const u16* hin = xb;
    for (int l = 0; l < 3; l++) {
        int FIN = fins[l];
        pack_all<<<NTOT, FIN, 0, stream>>>(p[l].Wq, p[l].bq, p[l].Wk, p[l].bk,
                                           p[l].Wv, p[l].bv, p[l].We, p[l].Ws, p[l].bs,
                                           Wc, b896, FIN);
        if (l == 0) gemm_v4<128><<<dim3(14, NBY), 256, 0, stream>>>(hin, Wc, b896, comb, kv);
        else        gemm_v4<64> <<<dim3(14, NBY), 256, 0, stream>>>(hin, Wc, b896, comb, kv);
        node_fused<<<2048, 256, 0, stream>>>(nctr + l, rowptr, csr_src, eattr_c,
            (const u16*)comb, kv, p[l].We, lng, lnb,
            (l == 2) ? nullptr : hbuf, (l == 2) ? (float*)d_out : nullptr);
        hin = (const u16*)hbuf;
    }
}

// Round 12
// 638.414 us; speedup vs baseline: 2.4432x; 2.4432x over previous
//
#include <hip/hip_runtime.h>
#include <hip/hip_bf16.h>
#include <math.h>

#define NNODES 50000
#define NEDGES 800000
#define HD     256   // HEADS*DHEAD
#define CW     384   // comb width: q(256) | qwe(64) | skip(64)
#define NTOT   896   // Wc rows: q(256)|qwe(64)|skip(64)|v(256)|k(256)
#define QS     0.18033688011112042f   // 0.125 * log2(e): fold softmax scale into exp2

typedef __hip_bfloat16 bf16;
typedef unsigned short u16;
typedef unsigned char  u8;
typedef unsigned int   u32;
typedef __attribute__((ext_vector_type(8))) short bf16x8;
typedef __attribute__((ext_vector_type(4))) float f32x4;
typedef __attribute__((ext_vector_type(2))) float f32x2;

__device__ __forceinline__ float lo16f(u32 u) { return __uint_as_float(u << 16); }
__device__ __forceinline__ float hi16f(u32 u) { return __uint_as_float(u & 0xFFFF0000u); }
__device__ __forceinline__ short f2s(float v) { __hip_bfloat16 h = __float2bfloat16(v); return *(short*)&h; }

// async global->LDS, 16B per lane; lds dest is wave-uniform base + lane*16 (linear)
__device__ __forceinline__ void gload_lds16(const void* g, void* l) {
    __builtin_amdgcn_global_load_lds(
        (const __attribute__((address_space(1))) void*)g,
        (__attribute__((address_space(3))) void*)l, 16, 0, 0);
}

// VALU cross-lane add within 16-lane groups
template<int CTRL>
__device__ __forceinline__ float dppadd(float x) {
    int t = __builtin_amdgcn_update_dpp(0, __float_as_int(x), CTRL, 0xF, 0xF, true);
    return x + __int_as_float(t);
}

// ---------------- CSR build ----------------
__global__ void hist_kernel(const int* __restrict__ dst, int* __restrict__ deg, int E) {
    int e = blockIdx.x * 256 + threadIdx.x;
    if (e < E) atomicAdd(&deg[dst[e]], 1);
}

__global__ void scanA(const int* __restrict__ deg, int* __restrict__ locincl,
                      int* __restrict__ blocksum, int n) {
    int tid = threadIdx.x;
    int i = blockIdx.x * 256 + tid;
    int v = (i < n) ? deg[i] : 0;
    int lane = tid & 63, w = tid >> 6;
    int s = v;
    #pragma unroll
    for (int off = 1; off < 64; off <<= 1) {
        int t = __shfl_up(s, off);
        if (lane >= off) s += t;
    }
    __shared__ int wsum[4];
    if (lane == 63) wsum[w] = s;
    __syncthreads();
    for (int ww = 0; ww < w; ww++) s += wsum[ww];
    if (i < n) locincl[i] = s;
    if (tid == 255) blocksum[blockIdx.x] = s;
}

__global__ void scanB(const int* __restrict__ blocksum, int* __restrict__ blockoff,
                      int nb, int* __restrict__ rowptr, int n) {
    int tid = threadIdx.x;
    int v = (tid < nb) ? blocksum[tid] : 0;
    int lane = tid & 63, w = tid >> 6;
    int s = v;
    #pragma unroll
    for (int off = 1; off < 64; off <<= 1) {
        int t = __shfl_up(s, off);
        if (lane >= off) s += t;
    }
    __shared__ int wsum[4];
    if (lane == 63) wsum[w] = s;
    __syncthreads();
    for (int ww = 0; ww < w; ww++) s += wsum[ww];
    if (tid < nb) blockoff[tid] = s - v;
    if (tid == 255) rowptr[n] = s;
}

__global__ void scanC(const int* __restrict__ deg, const int* __restrict__ locincl,
                      const int* __restrict__ blockoff,
                      int* __restrict__ rowptr, int* __restrict__ cursor, int n) {
    int i = blockIdx.x * 256 + threadIdx.x;
    if (i < n) {
        int ex = locincl[i] - deg[i] + blockoff[blockIdx.x];
        rowptr[i] = ex;
        cursor[i] = ex;
    }
}

// scatter + eattr permute fused: eattr read SEQUENTIALLY by edge id (64-B coalesced),
// converted to bf16 and written once to CSR position (random 32-B write).
__global__ void scatter_kernel(const int* __restrict__ src, const int* __restrict__ dst,
                               int* __restrict__ cursor, int* __restrict__ csr_src,
                               const float* __restrict__ eattr, u16* __restrict__ eattr_c, int E) {
    int e = blockIdx.x * 256 + threadIdx.x;
    if (e < E) {
        int d = dst[e];
        int p = atomicAdd(&cursor[d], 1);
        csr_src[p] = src[e];
        const float4* er = (const float4*)(eattr + (size_t)e * 16);
        float4 a = er[0], b = er[1], c = er[2], f = er[3];
        union { u16 s[16]; uint4 u[2]; } t;
        t.s[0]  = (u16)f2s(a.x); t.s[1]  = (u16)f2s(a.y); t.s[2]  = (u16)f2s(a.z); t.s[3]  = (u16)f2s(a.w);
        t.s[4]  = (u16)f2s(b.x); t.s[5]  = (u16)f2s(b.y); t.s[6]  = (u16)f2s(b.z); t.s[7]  = (u16)f2s(b.w);
        t.s[8]  = (u16)f2s(c.x); t.s[9]  = (u16)f2s(c.y); t.s[10] = (u16)f2s(c.z); t.s[11] = (u16)f2s(c.w);
        t.s[12] = (u16)f2s(f.x); t.s[13] = (u16)f2s(f.y); t.s[14] = (u16)f2s(f.z); t.s[15] = (u16)f2s(f.w);
        uint4* dstp = (uint4*)((u8*)eattr_c + (size_t)p * 32);
        dstp[0] = t.u[0];
        dstp[1] = t.u[1];
    }
}

// ---- x fp32 -> bf16 (once) ----
__global__ void xcast(const float* __restrict__ x, u16* __restrict__ xb) {
    int i = blockIdx.x * 256 + threadIdx.x;
    const float4* p = (const float4*)(x + (size_t)i * 8);
    float4 a = p[0], b = p[1];
    union { u16 s[8]; uint4 u; } t;
    t.s[0] = (u16)f2s(a.x); t.s[1] = (u16)f2s(a.y); t.s[2] = (u16)f2s(a.z); t.s[3] = (u16)f2s(a.w);
    t.s[4] = (u16)f2s(b.x); t.s[5] = (u16)f2s(b.y); t.s[6] = (u16)f2s(b.z); t.s[7] = (u16)f2s(b.w);
    *(uint4*)(xb + (size_t)i * 8) = t.u;
}

// ---- pack: 896 rows n-major bf16 [NTOT][K] + fp32 bias ----
// rows: q(0..255)*QS | qwe(256..319)*QS | skip(320..383) | v(384..639) | k(640..895)
__global__ void pack_all(const float* __restrict__ Wq, const float* __restrict__ bq,
                         const float* __restrict__ Wk, const float* __restrict__ bk,
                         const float* __restrict__ Wv, const float* __restrict__ bv,
                         const float* __restrict__ We,
                         const float* __restrict__ Ws, const float* __restrict__ bs,
                         bf16* __restrict__ Wc, float* __restrict__ b, int K) {
    int n = blockIdx.x, c = threadIdx.x;
    float v, bb;
    if (n < 256)      { v = Wq[(size_t)c * 256 + n] * QS;    bb = bq[n] * QS; }
    else if (n < 320) {
        int t = n - 256, h = t >> 4, j = t & 15;
        float s = 0.f, sb = 0.f;
        #pragma unroll 8
        for (int d = 0; d < 64; d++) {
            float wv = We[j * HD + h * 64 + d];
            s += Wq[(size_t)c * 256 + h * 64 + d] * wv;
            sb += bq[h * 64 + d] * wv;
        }
        v = s * QS; bb = sb * QS;
    }
    else if (n < 384) { v = Ws[(size_t)c * 64  + (n - 320)]; bb = bs[n - 320]; }
    else if (n < 640) { v = Wv[(size_t)c * 256 + (n - 384)]; bb = bv[n - 384]; }
    else              { v = Wk[(size_t)c * 256 + (n - 640)]; bb = bk[n - 640]; }
    Wc[(size_t)n * K + c] = __float2bfloat16(v);
    if (c == 0) b[n] = bb;
}

// ---------------- MFMA GEMM v4 (unchanged) ----------------
template<int K>
__global__ void __launch_bounds__(256) gemm_v4(
    const u16* __restrict__ A, const bf16* __restrict__ Wc, const float* __restrict__ bias,
    bf16* __restrict__ comb, u8* __restrict__ kv)
{
    constexpr int KS    = K / 32;
    constexpr int ITERS = 4;
    constexpr int ROWB  = K * 2;
    constexpr int TILEB = 64 * ROWB;
    constexpr int WSEG  = TILEB / 4;
    constexpr int NINST = WSEG / 1024;
    __shared__ __align__(16) u8 Ab[2][TILEB];
    __shared__ __align__(16) u8 TrB[4][2560];
    int tid = threadIdx.x, w = tid >> 6, lane = tid & 63;
    int cl = lane & 15, aq = lane >> 4;
    int chunk = blockIdx.x;
    int slab = blockIdx.y * (64 * ITERS);
    u8* myT = TrB[w];

    bf16x8 bfr[4][KS];
    #pragma unroll
    for (int t = 0; t < 4; t++)
        #pragma unroll
        for (int ks = 0; ks < KS; ks++)
            bfr[t][ks] = *(const bf16x8*)((const u16*)Wc +
                         (size_t)(chunk * 64 + t * 16 + cl) * K + ks * 32 + aq * 8);

    float4 bv[4];
    #pragma unroll
    for (int t = 0; t < 4; t++) bv[t] = *(const float4*)&bias[chunk * 64 + t * 16 + aq * 4];

    auto STAGE = [&](int b, int it) {
        int m0 = slab + it * 64;
        #pragma unroll
        for (int i = 0; i < NINST; i++) {
            int off = w * WSEG + i * 1024;
            int rowbase = off / ROWB;
            int row, gran;
            if constexpr (K == 64) { row = rowbase + (lane >> 3); gran = lane & 7;  }
            else                   { row = rowbase + (lane >> 4); gran = lane & 15; }
            int gr = m0 + row; if (gr >= NNODES) gr = NNODES - 1;
            int sg = gran ^ (row & 7);
            gload_lds16((const u8*)A + (size_t)gr * ROWB + sg * 16, Ab[b] + off);
        }
    };

    STAGE(0, 0);
    __syncthreads();
    int cur = 0;
    #pragma unroll
    for (int it = 0; it < ITERS; it++) {
        if (it + 1 < ITERS) STAGE(cur ^ 1, it + 1);

        int rowt = w * 16 + cl;
        bf16x8 a[KS];
        #pragma unroll
        for (int ks = 0; ks < KS; ks++)
            a[ks] = *(const bf16x8*)&Ab[cur][rowt * ROWB + (((ks * 4 + aq) ^ (rowt & 7)) << 4)];

        f32x4 acc[4] = {};
        #pragma unroll
        for (int t = 0; t < 4; t++)
            #pragma unroll
            for (int ks = 0; ks < KS; ks++)
                acc[t] = __builtin_amdgcn_mfma_f32_16x16x32_bf16(bfr[t][ks], a[ks], acc[t], 0, 0, 0);

        if (chunk < 10) {
            #pragma unroll
            for (int t = 0; t < 4; t++) {
                u32 lo = (u32)(u16)f2s(acc[t][0] + bv[t].x) | ((u32)(u16)f2s(acc[t][1] + bv[t].y) << 16);
                u32 hi = (u32)(u16)f2s(acc[t][2] + bv[t].z) | ((u32)(u16)f2s(acc[t][3] + bv[t].w) << 16);
                *(uint2*)(myT + cl * 160 + t * 32 + aq * 8) = make_uint2(lo, hi);
            }
            #pragma unroll
            for (int i = 0; i < 2; i++) {
                int r = i * 8 + (lane >> 3);
                uint4 vv = *(const uint4*)(myT + r * 160 + (lane & 7) * 16);
                int gr = slab + it * 64 + w * 16 + r;
                if (gr < NNODES) {
                    u8* dst = (chunk < 6) ? (u8*)comb + (size_t)gr * (CW * 2) + chunk * 128
                                          : kv + (size_t)gr * 768 + (chunk - 6) * 128;
                    *(uint4*)(dst + (lane & 7) * 16) = vv;
                }
            }
        } else {
            #pragma unroll
            for (int t = 0; t < 4; t++) {
                u32 pk = __builtin_amdgcn_cvt_pk_fp8_f32(acc[t][0] + bv[t].x, acc[t][1] + bv[t].y, 0, false);
                pk = __builtin_amdgcn_cvt_pk_fp8_f32(acc[t][2] + bv[t].z, acc[t][3] + bv[t].w, pk, true);
                *(u32*)(myT + cl * 80 + (t * 4 + aq) * 4) = pk;
            }
            {
                int r = lane >> 2;
                uint4 vv = *(const uint4*)(myT + r * 80 + (lane & 3) * 16);
                int gr = slab + it * 64 + w * 16 + r;
                if (gr < NNODES)
                    *(uint4*)(kv + (size_t)gr * 768 + 512 + (chunk - 10) * 64 + (lane & 3) * 16) = vv;
            }
        }
        __syncthreads();
        cur ^= 1;
    }
}

// ---------------- fused edge-logit + node aggregation + epilogue (R9 static form) ----------
// One wave per node (4 nodes/block), static grid. Merged kv gather (one SGPR row base),
// sequential bf16 eattr_c, 8-wide unrolled edge loop. No barriers.
__global__ void __launch_bounds__(256) node_fused(
    const int* __restrict__ rowptr, const int* __restrict__ csr_src,
    const u16* __restrict__ eattr_c, const u16* __restrict__ comb,
    const u8* __restrict__ kv,
    const float* __restrict__ We, const float* __restrict__ lng, const float* __restrict__ lnb,
    bf16* __restrict__ outB, float* __restrict__ outF)
{
    int tid = threadIdx.x, w = tid >> 6, lane = tid & 63;
    int n = blockIdx.x * 4 + w;                  // 12500 * 4 == NNODES exactly
    int hg = lane >> 4, j16 = lane & 15, coff = 4 * lane;
    __shared__ float sAV[4][256];
    __shared__ float sAE[4][64];

    const u16* crow = comb + (size_t)n * CW;
    uint2 qv = *(const uint2*)(crow + coff);     // q channels coff..coff+3 (pre-scaled by QS)
    float qf0 = lo16f(qv.x), qf1 = hi16f(qv.x), qf2 = lo16f(qv.y), qf3 = hi16f(qv.y);
    float qwe_r = __uint_as_float((u32)crow[256 + lane] << 16);   // qwe (pre-scaled)

    int e0 = __builtin_amdgcn_readfirstlane(rowptr[n]);
    int e1 = __builtin_amdgcn_readfirstlane(rowptr[n + 1]);

    float ss = 0.f, av0 = 0.f, av1 = 0.f, av2 = 0.f, av3 = 0.f, ae = 0.f;
    u32 vo = (u32)coff * 2u;          // byte offset in v region (0..504)
    u32 eo = (u32)j16 * 2u;           // bf16 byte offset in eattr_c row (0..30)

    auto EDGE = [&](int sm, int pos) {
        u32 s = (u32)__builtin_amdgcn_readfirstlane(sm);       // wave-uniform -> SGPR
        const u8* kvp = kv + (size_t)s * 768u;
        uint2 vw = *(const uint2*)(kvp + vo);
        u32   kw = *(const u32*)  (kvp + 512u + (u32)coff);
        float ea = lo16f((u32)*(const u16*)((const u8*)eattr_c + (size_t)(u32)pos * 32u + eo));
        f32x2 k01 = __builtin_amdgcn_cvt_pk_f32_fp8(kw, false);
        f32x2 k23 = __builtin_amdgcn_cvt_pk_f32_fp8(kw, true);
        float part = qf0 * k01[0] + qf1 * k01[1] + qf2 * k23[0] + qf3 * k23[1] + qwe_r * ea;
        part = dppadd<0xB1>(part);    // xor 1
        part = dppadd<0x4E>(part);    // xor 2
        part = dppadd<0x141>(part);   // xor 4 (row_half_mirror)
        part = dppadd<0x140>(part);   // xor 8 (row_mirror)
        float alpha = __builtin_amdgcn_exp2f(part);   // scale folded into q at pack time
        ss += alpha;
        ae += alpha * ea;
        av0 += alpha * lo16f(vw.x); av1 += alpha * hi16f(vw.x);
        av2 += alpha * lo16f(vw.y); av3 += alpha * hi16f(vw.y);
    };

    const int* cs = csr_src;
    int i = e0;
    int m0 = 0, m1 = 0, m2 = 0, m3 = 0, m4 = 0, m5 = 0, m6 = 0, m7 = 0;
    if (i + 7 < e1) {
        m0 = cs[i];     m1 = cs[i + 1]; m2 = cs[i + 2]; m3 = cs[i + 3];
        m4 = cs[i + 4]; m5 = cs[i + 5]; m6 = cs[i + 6]; m7 = cs[i + 7];
    }
    for (; i + 15 < e1; i += 8) {
        int n0 = cs[i + 8],  n1 = cs[i + 9],  n2 = cs[i + 10], n3 = cs[i + 11];
        int n4 = cs[i + 12], n5 = cs[i + 13], n6 = cs[i + 14], n7 = cs[i + 15];
        EDGE(m0, i);     EDGE(m1, i + 1); EDGE(m2, i + 2); EDGE(m3, i + 3);
        EDGE(m4, i + 4); EDGE(m5, i + 5); EDGE(m6, i + 6); EDGE(m7, i + 7);
        m0 = n0; m1 = n1; m2 = n2; m3 = n3; m4 = n4; m5 = n5; m6 = n6; m7 = n7;
    }
    if (i + 7 < e1) {
        EDGE(m0, i);     EDGE(m1, i + 1); EDGE(m2, i + 2); EDGE(m3, i + 3);
        EDGE(m4, i + 4); EDGE(m5, i + 5); EDGE(m6, i + 6); EDGE(m7, i + 7);
        i += 8;
    }
    for (; i < e1; ++i) EDGE(cs[i], i);

    // epilogue (all waves active; same-wave LDS transpose, no barrier)
    float inv = (ss > 0.f) ? 1.f / ss : 0.f;     // uniform within each 16-lane head group
    *(float4*)&sAV[w][coff] = make_float4(av0 * inv, av1 * inv, av2 * inv, av3 * inv);
    sAE[w][lane] = ae * inv;

    int d = lane;
    float val = 0.f;
    #pragma unroll
    for (int h = 0; h < 4; h++) {
        float xv = sAV[w][h * 64 + d];
        #pragma unroll
        for (int j = 0; j < 16; j++) xv += sAE[w][h * 16 + j] * We[j * HD + h * 64 + d];
        val += xv;
    }
    val = val * 0.25f + __uint_as_float((u32)crow[320 + d] << 16);   // head mean + skip

    float m = val;
    #pragma unroll
    for (int off = 1; off < 64; off <<= 1) m += __shfl_xor(m, off);
    m *= (1.f / 64.f);
    float diff = val - m;
    float vr = diff * diff;
    #pragma unroll
    for (int off = 1; off < 64; off <<= 1) vr += __shfl_xor(vr, off);
    vr *= (1.f / 64.f);
    float y = diff * rsqrtf(vr + 1e-5f) * lng[d] + lnb[d];
    float ge = 0.5f * y * (1.f + erff(y * 0.70710678118654752f));    // exact GELU
    if (outF) outF[(size_t)n * 64 + d] = ge;
    else      outB[(size_t)n * 64 + d] = __float2bfloat16(ge);
}

extern "C" void kernel_launch(void* const* d_in, const int* in_sizes, int n_in,
                              void* d_out, int out_size, void* d_ws, size_t ws_size,
                              hipStream_t stream)
{
    const float* x     = (const float*)d_in[0];
    const int*   eidx  = (const int*)d_in[1];
    const float* eattr = (const float*)d_in[2];
    struct P { const float *Wq,*bq,*Wk,*bk,*Wv,*bv,*We,*Ws,*bs; };
    P p[3];
    for (int l = 0; l < 3; l++) {
        int base = 3 + l * 9;
        p[l].Wq = (const float*)d_in[base + 0]; p[l].bq = (const float*)d_in[base + 1];
        p[l].Wk = (const float*)d_in[base + 2]; p[l].bk = (const float*)d_in[base + 3];
        p[l].Wv = (const float*)d_in[base + 4]; p[l].bv = (const float*)d_in[base + 5];
        p[l].We = (const float*)d_in[base + 6];
        p[l].Ws = (const float*)d_in[base + 7]; p[l].bs = (const float*)d_in[base + 8];
    }
    const float* lng = (const float*)d_in[30];
    const float* lnb = (const float*)d_in[31];

    // Workspace: ~127 MB
    char* ws = (char*)d_ws;
    size_t off = 0;
    auto alloc = [&](size_t bytes) { void* pp = ws + off; off += (bytes + 255) & ~(size_t)255; return pp; };
    int*   rowptr   = (int*)  alloc((NNODES + 1) * 4);
    int*   cursor   = (int*)  alloc(NNODES * 4);
    int*   deg      = (int*)  alloc(NNODES * 4);
    int*   blocksum = (int*)  alloc(256 * 4);
    int*   blockoff = (int*)  alloc(256 * 4);
    int*   csr_src  = (int*)  alloc((size_t)NEDGES * 4);        // 3.2 MB
    u16*   eattr_c  = (u16*)  alloc((size_t)NEDGES * 16 * 2);   // 25.6 MB bf16, CSR order
    bf16*  hbuf     = (bf16*) alloc((size_t)NNODES * 64 * 2);   // 6.4 MB
    u16*   xb       = (u16*)  alloc((size_t)NNODES * 128 * 2);  // 12.8 MB bf16 x
    bf16*  comb     = (bf16*) alloc((size_t)NNODES * CW * 2);   // 38.4 MB: q|qwe|skip
    u8*    kv       = (u8*)   alloc((size_t)NNODES * 768);      // 38.4 MB: v(512B)|k(256B)
    bf16*  Wc       = (bf16*) alloc((size_t)NTOT * 128 * 2);    // 229 KB
    float* b896     = (float*)alloc(NTOT * 4);
    (void)ws_size;

    const int* srcArr = eidx;           // edge_index[0]
    const int* dstArr = eidx + NEDGES;  // edge_index[1]

    // CSR build (+fused eattr permute) + x cast
    int NB = (NNODES + 255) / 256;
    (void)hipMemsetAsync(deg, 0, NNODES * 4, stream);
    hist_kernel<<<(NEDGES + 255) / 256, 256, 0, stream>>>(dstArr, deg, NEDGES);
    scanA<<<NB, 256, 0, stream>>>(deg, cursor, blocksum, NNODES);
    scanB<<<1, 256, 0, stream>>>(blocksum, blockoff, NB, rowptr, NNODES);
    scanC<<<NB, 256, 0, stream>>>(deg, cursor, blockoff, rowptr, cursor, NNODES);
    scatter_kernel<<<(NEDGES + 255) / 256, 256, 0, stream>>>(srcArr, dstArr, cursor,
                                                             csr_src, eattr, eattr_c, NEDGES);
    xcast<<<(NNODES * 128 / 8 + 255) / 256, 256, 0, stream>>>(x, xb);

    int NBY = (NNODES + 255) / 256;   // 196 m-slabs of 256 rows
    int fins[3] = {128, 64, 64};

    const u16* hin = xb;
    for (int l = 0; l < 3; l++) {
        int FIN = fins[l];
        pack_all<<<NTOT, FIN, 0, stream>>>(p[l].Wq, p[l].bq, p[l].Wk, p[l].bk,
                                           p[l].Wv, p[l].bv, p[l].We, p[l].Ws, p[l].bs,
                                           Wc, b896, FIN);
        if (l == 0) gemm_v4<128><<<dim3(14, NBY), 256, 0, stream>>>(hin, Wc, b896, comb, kv);
        else        gemm_v4<64> <<<dim3(14, NBY), 256, 0, stream>>>(hin, Wc, b896, comb, kv);
        node_fused<<<NNODES / 4, 256, 0, stream>>>(rowptr, csr_src, eattr_c,
            (const u16*)comb, kv, p[l].We, lng, lnb,
            (l == 2) ? nullptr : hbuf, (l == 2) ? (float*)d_out : nullptr);
        hin = (const u16*)hbuf;
    }
}